// Round 10
// baseline (79.171 us; speedup 1.0000x reference)
//
#include <hip/hip_runtime.h>
#include <math.h>

#define NFEAT 16
#define NRULE 64
#define TPW 2        // 16-sample tiles per wave

typedef _Float16 half8 __attribute__((ext_vector_type(8)));
typedef float    f4    __attribute__((ext_vector_type(4)));
union F4H8 { float4 f; half8 h; };

// Single fused kernel: each wave builds its MFMA B-operand fragments from
// mu/sigma/rho in registers (no prep dispatch, no table), then runs the
// MFMA rule loop. f16-split GEMM: A = [Xh | Xl] (K=32), B1 = [Wh;Wh],
// B2 = [Wl;Wl] -> mfma(A,B1)+mfma(A,B2) = X*W to fp32 rounding.
// A-frag: m = lane&15 (sample), k = quad*8+j; quads 0,1 = Xh, 2,3 = Xl.
// B-frag: n = lane&15 (rule), same k -> feats fb = (quad&1)*8.
// C/D: col = lane&15 (rule), row = quad*4+reg (sample). [verified R9 pass]
__global__ __launch_bounds__(256, 4) void fuzzy_fused(const float* __restrict__ x,
                                                      const float* __restrict__ mu,
                                                      const float* __restrict__ sigma,
                                                      const float* __restrict__ rho,
                                                      float* __restrict__ out, int n) {
    const float L2E = 1.4426950408889634f;
    const int tid  = threadIdx.x;
    const int L    = tid & 63;
    const int quad = L >> 4;
    const int m    = L & 15;
    const int wv   = __builtin_amdgcn_readfirstlane(tid >> 6);
    const int fb   = (quad & 1) * 8;

    // ---- issue x loads first (2 tiles x 32 B/lane), in flight during build
    const int tbase = (blockIdx.x * 4 + wv) * TPW;     // tile index base
    float4 xa[TPW], xb[TPW];
#pragma unroll
    for (int t = 0; t < TPW; ++t) {
        int tb = (tbase + t) * 16;
        int sc = tb + m < n ? tb + m : n - 1;
        const float4* xp = (const float4*)(x + (size_t)sc * NFEAT + fb);
        xa[t] = xp[0]; xb[t] = xp[1];
    }

    // ---- in-register fragment build (replaces the prep dispatch) ----
    F4H8 b1[4], b2[4], r1[4], r2[4];
    float Pv[4], KLv[4], Bv[4];
    bool u = true;
#pragma unroll
    for (int T = 0; T < 4; ++T) {
        int rule = T * 16 + m;
        const float* mrow = mu    + rule * NFEAT + fb;
        const float* srow = sigma + rule * NFEAT + fb;
        const float* rrow = rho   + rule * (NFEAT + 1) + fb;
        float s0 = sigma[rule * NFEAT];
        float c0 = 1.0f / (2.0f * s0 * s0);
        float kp = 0.0f;
#pragma unroll
        for (int j = 0; j < 8; ++j) {
            float mm = mrow[j], ss = srow[j];
            float inv = 1.0f / (2.0f * ss * ss);
            u = u && (inv == c0);
            float Bw = 2.0f * inv * mm * L2E;
            _Float16 bh = (_Float16)Bw;
            b1[T].h[j] = bh;
            b2[T].h[j] = (_Float16)(Bw - (float)bh);
            float Rw = rrow[j];
            _Float16 rh_ = (_Float16)Rw;
            r1[T].h[j] = rh_;
            r2[T].h[j] = (_Float16)(Rw - (float)rh_);
            kp = fmaf(-inv * mm, mm, kp);
        }
        Pv[T]  = -c0 * L2E;
        KLv[T] = (kp + __shfl_xor(kp, 16)) * L2E;   // other 8 feats from quad^1
        Bv[T]  = rho[rule * (NFEAT + 1) + NFEAT];
    }
    // 64 lanes x 4 T cover all 64 rules x 16 feats: wave ballot = global flag.
    const int flag =
        __builtin_amdgcn_readfirstlane((int)(__ballot(u) == ~0ull));

    if (flag) {
#pragma unroll
        for (int t = 0; t < TPW; ++t) {
            int tb = (tbase + t) * 16;
            if (tb >= n) break;
            float xv[8] = {xa[t].x, xa[t].y, xa[t].z, xa[t].w,
                           xb[t].x, xb[t].y, xb[t].z, xb[t].w};
            F4H8 af;
            float qp = 0.0f;
#pragma unroll
            for (int j = 0; j < 8; ++j) {
                _Float16 h = (_Float16)xv[j];
                af.h[j] = (quad < 2) ? h : (_Float16)(xv[j] - (float)h);
                qp = fmaf(xv[j], xv[j], qp);
            }
            float Qf = qp + __shfl_xor(qp, 16);     // Q[sample m], all lanes
            float Qr[4];
#pragma unroll
            for (int p = 0; p < 4; ++p) Qr[p] = __shfl(Qf, quad * 4 + p);

            f4 nsum = {0.f, 0.f, 0.f, 0.f}, dsum = {0.f, 0.f, 0.f, 0.f};
#pragma unroll
            for (int T = 0; T < 4; ++T) {
                f4 z4 = {0.f, 0.f, 0.f, 0.f};
                f4 accL = __builtin_amdgcn_mfma_f32_16x16x32_f16(af.h, b1[T].h, z4, 0, 0, 0);
                accL    = __builtin_amdgcn_mfma_f32_16x16x32_f16(af.h, b2[T].h, accL, 0, 0, 0);
                f4 accZ = __builtin_amdgcn_mfma_f32_16x16x32_f16(af.h, r1[T].h, z4, 0, 0, 0);
                accZ    = __builtin_amdgcn_mfma_f32_16x16x32_f16(af.h, r2[T].h, accZ, 0, 0, 0);
#pragma unroll
                for (int p = 0; p < 4; ++p) {
                    float l = fmaf(Pv[T], Qr[p], accL[p] + KLv[T]);
                    float w = __builtin_amdgcn_exp2f(l);
                    float zf = accZ[p] + Bv[T];
                    nsum[p] = fmaf(zf, w, nsum[p]);
                    dsum[p] += w;
                }
            }
#pragma unroll
            for (int d = 1; d < 16; d <<= 1) {
#pragma unroll
                for (int p = 0; p < 4; ++p) {
                    nsum[p] += __shfl_xor(nsum[p], d);
                    dsum[p] += __shfl_xor(dsum[p], d);
                }
            }
            if (m == 0) {                            // 4 writer lanes
                float4 o;
                o.x = nsum[0] * __builtin_amdgcn_rcpf(dsum[0] + 1e-13f);
                o.y = nsum[1] * __builtin_amdgcn_rcpf(dsum[1] + 1e-13f);
                o.z = nsum[2] * __builtin_amdgcn_rcpf(dsum[2] + 1e-13f);
                o.w = nsum[3] * __builtin_amdgcn_rcpf(dsum[3] + 1e-13f);
                ((float4*)(out + tb))[quad] = o;
            }
        }
    } else {
        // General fallback (arbitrary sigma; not taken for this input).
#pragma unroll
        for (int t = 0; t < TPW; ++t) {
            int tb = (tbase + t) * 16;
            if (tb >= n) break;
            int s = tb + m;
            const float4* xp = (const float4*)(x + (size_t)s * NFEAT);
            float4 a = xp[0], b = xp[1], c = xp[2], d = xp[3];
            float xs[NFEAT] = {a.x,a.y,a.z,a.w, b.x,b.y,b.z,b.w,
                               c.x,c.y,c.z,c.w, d.x,d.y,d.z,d.w};
            float num = 0.0f, den = 0.0f;
            for (int r = quad * 16; r < quad * 16 + 16; ++r) {
                float z = rho[r * (NFEAT + 1) + NFEAT];
                float l = 0.0f;
                for (int aa = 0; aa < NFEAT; ++aa) {
                    float mm = mu[r * NFEAT + aa];
                    float ss = sigma[r * NFEAT + aa];
                    float inv = 1.0f / (2.0f * ss * ss);
                    float dd = xs[aa] - mm;
                    l = fmaf(-inv * dd, dd, l);
                    z = fmaf(rho[r * (NFEAT + 1) + aa], xs[aa], z);
                }
                float w = __builtin_amdgcn_exp2f(l * L2E);
                num = fmaf(z, w, num);
                den += w;
            }
            num += __shfl_xor(num, 16); den += __shfl_xor(den, 16);
            num += __shfl_xor(num, 32); den += __shfl_xor(den, 32);
            if (L < 16) out[tb + L] = num / (den + 1e-13f);
        }
    }
}

extern "C" void kernel_launch(void* const* d_in, const int* in_sizes, int n_in,
                              void* d_out, int out_size, void* d_ws, size_t ws_size,
                              hipStream_t stream) {
    const float* x     = (const float*)d_in[0];   // [N,16]
    const float* mu    = (const float*)d_in[1];   // [64,16]
    const float* sigma = (const float*)d_in[2];   // [64,16]
    const float* rho   = (const float*)d_in[3];   // [64,17]
    float* out = (float*)d_out;

    int n = in_sizes[0] / NFEAT;                  // 131072

    int blocks = (n + 16 * 4 * TPW - 1) / (16 * 4 * TPW);  // 1024
    fuzzy_fused<<<blocks, 256, 0, stream>>>(x, mu, sigma, rho, out, n);
}

// Round 11
// 74.640 us; speedup vs baseline: 1.0607x; 1.0607x over previous
//
#include <hip/hip_runtime.h>
#include <math.h>

#define NFEAT 16
#define NRULE 64
#define TPW 2        // 16-sample tiles per wave

typedef _Float16 half8 __attribute__((ext_vector_type(8)));
typedef float    f4    __attribute__((ext_vector_type(4)));
union F4H8 { float4 f; half8 h; };

// Single fused kernel: each wave builds its MFMA B-operand fragments from
// mu/sigma/rho in registers (no prep dispatch, no table), then runs the
// MFMA rule loop. f16-split GEMM: A = [Xh | Xl] (K=32), B1 = [Wh;Wh],
// B2 = [Wl;Wl] -> mfma(A,B1)+mfma(A,B2) = X*W to fp32 rounding.
// A-frag: m = lane&15 (sample), k = quad*8+j; quads 0,1 = Xh, 2,3 = Xl.
// B-frag: n = lane&15 (rule), same k -> feats fb = (quad&1)*8.
// C/D: col = lane&15 (rule), row = quad*4+reg (sample). [verified R9 pass]
//
// R10 lesson: sigma-uniformity via float equality of two separately-codegen'd
// expressions (inv == c0) silently failed under -O3 -> fallback ran (absmax
// was scalar-exact 2^-40). Test input BITS instead: sigma bits equal implies
// inv equal, independent of codegen.
__global__ __launch_bounds__(256, 4) void fuzzy_fused(const float* __restrict__ x,
                                                      const float* __restrict__ mu,
                                                      const float* __restrict__ sigma,
                                                      const float* __restrict__ rho,
                                                      float* __restrict__ out, int n) {
    const float L2E = 1.4426950408889634f;
    const int tid  = threadIdx.x;
    const int L    = tid & 63;
    const int quad = L >> 4;
    const int m    = L & 15;
    const int wv   = __builtin_amdgcn_readfirstlane(tid >> 6);
    const int fb   = (quad & 1) * 8;

    // ---- issue x loads first (2 tiles x 32 B/lane), in flight during build
    const int tbase = (blockIdx.x * 4 + wv) * TPW;     // tile index base
    float4 xa[TPW], xb[TPW];
#pragma unroll
    for (int t = 0; t < TPW; ++t) {
        int tb = (tbase + t) * 16;
        int sc = tb + m < n ? tb + m : n - 1;
        const float4* xp = (const float4*)(x + (size_t)sc * NFEAT + fb);
        xa[t] = xp[0]; xb[t] = xp[1];
    }

    // ---- in-register fragment build (replaces the prep dispatch) ----
    F4H8 b1[4], b2[4], r1[4], r2[4];
    float Pv[4], KLv[4], Bv[4];
    bool u = true;
#pragma unroll
    for (int T = 0; T < 4; ++T) {
        int rule = T * 16 + m;
        const float* mrow = mu    + rule * NFEAT + fb;
        const float* srow = sigma + rule * NFEAT + fb;
        const float* rrow = rho   + rule * (NFEAT + 1) + fb;
        float s0 = sigma[rule * NFEAT];
        float c0 = 1.0f / (2.0f * s0 * s0);
        unsigned s0bits = __float_as_uint(s0);
        float kp = 0.0f;
#pragma unroll
        for (int j = 0; j < 8; ++j) {
            float mm = mrow[j], ss = srow[j];
            float inv = 1.0f / (2.0f * ss * ss);
            u = u && (__float_as_uint(ss) == s0bits);   // bitwise: codegen-proof
            float Bw = 2.0f * inv * mm * L2E;
            _Float16 bh = (_Float16)Bw;
            b1[T].h[j] = bh;
            b2[T].h[j] = (_Float16)(Bw - (float)bh);
            float Rw = rrow[j];
            _Float16 rh_ = (_Float16)Rw;
            r1[T].h[j] = rh_;
            r2[T].h[j] = (_Float16)(Rw - (float)rh_);
            kp = fmaf(-inv * mm, mm, kp);
        }
        Pv[T]  = -c0 * L2E;
        KLv[T] = (kp + __shfl_xor(kp, 16)) * L2E;   // other 8 feats from quad^1
        Bv[T]  = rho[rule * (NFEAT + 1) + NFEAT];
    }
    // 64 lanes x 4 T cover all 64 rules x 16 feats: wave ballot = global flag.
    const int flag =
        __builtin_amdgcn_readfirstlane((int)(__ballot(u) == ~0ull));

    if (flag) {
#pragma unroll
        for (int t = 0; t < TPW; ++t) {
            int tb = (tbase + t) * 16;
            if (tb >= n) break;
            float xv[8] = {xa[t].x, xa[t].y, xa[t].z, xa[t].w,
                           xb[t].x, xb[t].y, xb[t].z, xb[t].w};
            F4H8 af;
            float qp = 0.0f;
#pragma unroll
            for (int j = 0; j < 8; ++j) {
                _Float16 h = (_Float16)xv[j];
                af.h[j] = (quad < 2) ? h : (_Float16)(xv[j] - (float)h);
                qp = fmaf(xv[j], xv[j], qp);
            }
            float Qf = qp + __shfl_xor(qp, 16);     // Q[sample m], all lanes
            float Qr[4];
#pragma unroll
            for (int p = 0; p < 4; ++p) Qr[p] = __shfl(Qf, quad * 4 + p);

            f4 nsum = {0.f, 0.f, 0.f, 0.f}, dsum = {0.f, 0.f, 0.f, 0.f};
#pragma unroll
            for (int T = 0; T < 4; ++T) {
                f4 z4 = {0.f, 0.f, 0.f, 0.f};
                f4 accL = __builtin_amdgcn_mfma_f32_16x16x32_f16(af.h, b1[T].h, z4, 0, 0, 0);
                accL    = __builtin_amdgcn_mfma_f32_16x16x32_f16(af.h, b2[T].h, accL, 0, 0, 0);
                f4 accZ = __builtin_amdgcn_mfma_f32_16x16x32_f16(af.h, r1[T].h, z4, 0, 0, 0);
                accZ    = __builtin_amdgcn_mfma_f32_16x16x32_f16(af.h, r2[T].h, accZ, 0, 0, 0);
#pragma unroll
                for (int p = 0; p < 4; ++p) {
                    float l = fmaf(Pv[T], Qr[p], accL[p] + KLv[T]);
                    float w = __builtin_amdgcn_exp2f(l);
                    float zf = accZ[p] + Bv[T];
                    nsum[p] = fmaf(zf, w, nsum[p]);
                    dsum[p] += w;
                }
            }
#pragma unroll
            for (int d = 1; d < 16; d <<= 1) {
#pragma unroll
                for (int p = 0; p < 4; ++p) {
                    nsum[p] += __shfl_xor(nsum[p], d);
                    dsum[p] += __shfl_xor(dsum[p], d);
                }
            }
            if (m == 0) {                            // 4 writer lanes
                float4 o;
                o.x = nsum[0] * __builtin_amdgcn_rcpf(dsum[0] + 1e-13f);
                o.y = nsum[1] * __builtin_amdgcn_rcpf(dsum[1] + 1e-13f);
                o.z = nsum[2] * __builtin_amdgcn_rcpf(dsum[2] + 1e-13f);
                o.w = nsum[3] * __builtin_amdgcn_rcpf(dsum[3] + 1e-13f);
                ((float4*)(out + tb))[quad] = o;
            }
        }
    } else {
        // General fallback (arbitrary sigma; not taken for this input).
#pragma unroll
        for (int t = 0; t < TPW; ++t) {
            int tb = (tbase + t) * 16;
            if (tb >= n) break;
            int s = tb + m;
            const float4* xp = (const float4*)(x + (size_t)s * NFEAT);
            float4 a = xp[0], b = xp[1], c = xp[2], d = xp[3];
            float xs[NFEAT] = {a.x,a.y,a.z,a.w, b.x,b.y,b.z,b.w,
                               c.x,c.y,c.z,c.w, d.x,d.y,d.z,d.w};
            float num = 0.0f, den = 0.0f;
            for (int r = quad * 16; r < quad * 16 + 16; ++r) {
                float z = rho[r * (NFEAT + 1) + NFEAT];
                float l = 0.0f;
                for (int aa = 0; aa < NFEAT; ++aa) {
                    float mm = mu[r * NFEAT + aa];
                    float ss = sigma[r * NFEAT + aa];
                    float inv = 1.0f / (2.0f * ss * ss);
                    float dd = xs[aa] - mm;
                    l = fmaf(-inv * dd, dd, l);
                    z = fmaf(rho[r * (NFEAT + 1) + aa], xs[aa], z);
                }
                float w = __builtin_amdgcn_exp2f(l * L2E);
                num = fmaf(z, w, num);
                den += w;
            }
            num += __shfl_xor(num, 16); den += __shfl_xor(den, 16);
            num += __shfl_xor(num, 32); den += __shfl_xor(den, 32);
            if (L < 16) out[tb + L] = num / (den + 1e-13f);
        }
    }
}

extern "C" void kernel_launch(void* const* d_in, const int* in_sizes, int n_in,
                              void* d_out, int out_size, void* d_ws, size_t ws_size,
                              hipStream_t stream) {
    const float* x     = (const float*)d_in[0];   // [N,16]
    const float* mu    = (const float*)d_in[1];   // [64,16]
    const float* sigma = (const float*)d_in[2];   // [64,16]
    const float* rho   = (const float*)d_in[3];   // [64,17]
    float* out = (float*)d_out;

    int n = in_sizes[0] / NFEAT;                  // 131072

    int blocks = (n + 16 * 4 * TPW - 1) / (16 * 4 * TPW);  // 1024
    fuzzy_fused<<<blocks, 256, 0, stream>>>(x, mu, sigma, rho, out, n);
}